// Round 6
// baseline (684.950 us; speedup 1.0000x reference)
//
#include <hip/hip_runtime.h>
#include <hip/hip_bf16.h>

// One-hot expansion: mask [1,1,256,256,48] fp32 labels in 0..40 ->
// out [1,40,256,256,48] fp32, out[n,v] = (mask[v] == n+1).
//
// History: R1 one-plane-per-block = 474 us total (~155 us dispatch, never
// visible in top-5 under the ~318 us harness fills). R2 nt-stores neutral.
// R4 G=8 planes/block 491. R5 reg-resident mask + 40 bursts 490.
// R6 (x3 replicate): +140 us for 2 extra passes -> marginal pass = 70 us
// = >7 TB/s pure-write; so marginal mask reads HIT cache and pure writes
// beat the 6.3 TB/s copy ceiling. Pass 1's 155 us is the anomaly: either
// fill-hangover (LLC 100% dirty from the 2 GB poison fill -> our
// allocations drain its writebacks) or block-churn (122,880 short-lived
// blocks, 1 load+1 store each).
//
// R7: adopt the fill kernel's own structure -- 2048 PERSISTENT blocks,
// grid-stride interleave: all threads advance together, one coherent
// linear write front across the whole 503 MB output (n,v4 maintained
// incrementally from the linear output index). 4 internal sweeps
// (identical values -> benign rewrite) to force dispatch > 330 us so OUR
// counters finally appear in top-5. Decision table:
//   FETCH ~50 MB   -> mask cache-resident (Story B);  FETCH ~2 GB -> Story A.
//   per-sweep steady state ~80 us -> structure roofline; ship REPEAT=1.
//   per-sweep ~150 us -> mixed read/write cap; try LDS-staged mask.

constexpr int V  = 256 * 256 * 48;      // floats per plane
constexpr int V4 = V / 4;               // 786,432 float4 per plane
constexpr int N_LABELS = 40;
constexpr long TOTAL4 = (long)V4 * N_LABELS;  // 31,457,280 float4 outputs
constexpr int TPB  = 256;
constexpr int NBLK = 2048;              // 8 blocks/CU, persistent
constexpr int T    = TPB * NBLK;        // 524,288 threads = 8 MB front/step
constexpr int ITER = (int)(TOTAL4 / T); // 60 exact
constexpr int REPEAT = 4;               // diagnostic sweeps; winner ships 1

typedef float f32x4 __attribute__((ext_vector_type(4)));

__global__ __launch_bounds__(TPB)
void onehot_kernel(const float* __restrict__ mask, float* __restrict__ out) {
    const int tid = blockIdx.x * TPB + threadIdx.x;

    for (int r = 0; r < REPEAT; ++r) {
        // linear float4 output index = tid + j*T; track (n, v4) incrementally.
        int n  = 0;             // tid < V4 always (524,288 < 786,432)
        int v4 = tid;
        for (int j = 0; j < ITER; ++j) {
            const f32x4 m = *reinterpret_cast<const f32x4*>(mask + (size_t)v4 * 4);
            const float lab = (float)(n + 1);
            f32x4 o;
            o.x = (m.x == lab) ? 1.0f : 0.0f;
            o.y = (m.y == lab) ? 1.0f : 0.0f;
            o.z = (m.z == lab) ? 1.0f : 0.0f;
            o.w = (m.w == lab) ? 1.0f : 0.0f;
            *reinterpret_cast<f32x4*>(out + ((size_t)n * V4 + (size_t)v4) * 4) = o;

            v4 += T;                       // advance the front (T < V4: at most one wrap)
            if (v4 >= V4) { v4 -= V4; n += 1; }
        }
    }
}

extern "C" void kernel_launch(void* const* d_in, const int* in_sizes, int n_in,
                              void* d_out, int out_size, void* d_ws, size_t ws_size,
                              hipStream_t stream) {
    const float* mask = (const float*)d_in[0];
    float* out = (float*)d_out;

    onehot_kernel<<<dim3(NBLK), TPB, 0, stream>>>(mask, out);
}

// Round 7
// 500.889 us; speedup vs baseline: 1.3675x; 1.3675x over previous
//
#include <hip/hip_runtime.h>
#include <hip/hip_bf16.h>

// One-hot expansion: mask [1,1,256,256,48] fp32 labels in 0..40 ->
// out [1,40,256,256,48] fp32, out[n,v] = (mask[v] == n+1).
//
// History: R1 one-plane-per-block 474 us total (kernel ~155 us; harness
// poison-fill ~320 us is in the timed graph = our floor). R2 nt neutral.
// R4 G=8 interleave 491. R5 reg-resident bursts 490. R6 z-replicate x3:
// marginal pass ~70-98 us. R7 persistent grid-stride x4 sweeps: kernel
// ~365 us = 91 us/sweep AVERAGE -- better than R1's 155 us sweep, but
// ambiguous between {uniform 91/sweep} and {155 first + 70 marginal}.
// Note: our dispatch (365 us) STILL didn't surface in the top-5 counter
// table despite exceeding the fills -- counters are unobtainable for this
// kernel; all reasoning is timing arithmetic.
//
// R8 = R7 structure, REPEAT=1 (the decisive experiment IS the ship
// candidate): 2048 persistent blocks, fill-style coherent linear write
// front over the 503 MB output, (n,v4) tracked incrementally, mask reads
// hit L2/LLC (12.6 MB footprint). Downside bounded at neutral (~475);
// uniform-sweep story predicts ~415.

constexpr int V  = 256 * 256 * 48;      // floats per plane
constexpr int V4 = V / 4;               // 786,432 float4 per plane
constexpr int N_LABELS = 40;
constexpr long TOTAL4 = (long)V4 * N_LABELS;  // 31,457,280 float4 outputs
constexpr int TPB  = 256;
constexpr int NBLK = 2048;              // 8 blocks/CU, persistent
constexpr int T    = TPB * NBLK;        // 524,288 threads = 8 MB front/step
constexpr int ITER = (int)(TOTAL4 / T); // 60 exact

typedef float f32x4 __attribute__((ext_vector_type(4)));

__global__ __launch_bounds__(TPB)
void onehot_kernel(const float* __restrict__ mask, float* __restrict__ out) {
    const int tid = blockIdx.x * TPB + threadIdx.x;

    // linear float4 output index = tid + j*T; track (n, v4) incrementally.
    int n  = 0;             // tid < V4 always (524,288 < 786,432)
    int v4 = tid;
    for (int j = 0; j < ITER; ++j) {
        const f32x4 m = *reinterpret_cast<const f32x4*>(mask + (size_t)v4 * 4);
        const float lab = (float)(n + 1);
        f32x4 o;
        o.x = (m.x == lab) ? 1.0f : 0.0f;
        o.y = (m.y == lab) ? 1.0f : 0.0f;
        o.z = (m.z == lab) ? 1.0f : 0.0f;
        o.w = (m.w == lab) ? 1.0f : 0.0f;
        *reinterpret_cast<f32x4*>(out + ((size_t)n * V4 + (size_t)v4) * 4) = o;

        v4 += T;                       // advance the front (T < V4: at most one wrap)
        if (v4 >= V4) { v4 -= V4; n += 1; }
    }
}

extern "C" void kernel_launch(void* const* d_in, const int* in_sizes, int n_in,
                              void* d_out, int out_size, void* d_ws, size_t ws_size,
                              hipStream_t stream) {
    const float* mask = (const float*)d_in[0];
    float* out = (float*)d_out;

    onehot_kernel<<<dim3(NBLK), TPB, 0, stream>>>(mask, out);
}

// Round 8
// 474.641 us; speedup vs baseline: 1.4431x; 1.0553x over previous
//
#include <hip/hip_runtime.h>
#include <hip/hip_bf16.h>

// One-hot expansion: mask [1,1,256,256,48] fp32 labels in 0..40 ->
// out [1,40,256,256,48] fp32, out[n,v] = (mask[v] == n+1).
//
// R9 = REVERT to the verified-best R1 structure (474.2 us).
//
// Session ledger (kernel time = total - ~320 us harness poison fill,
// which is in the timed graph and untouchable):
//   R1 block-churn, 1 plane/block:            ~155 us  (best, 474 total)
//   R2 + nt stores:                            neutral
//   R4 G=8 planes/block interleave:           ~170 us
//   R5 reg-resident mask + 40 bursts:         ~170 us
//   R6 R1 x3 (z-replicate):                   155 + 2x70
//   R7 persistent grid-stride x4:             180 + 3x62
//   R8 persistent grid-stride x1:             ~180 us
// Model: first output sweep after the 2 GB poison fill pays a fixed
// ~75-95 us memory-system transition premium (dirty-LLC writeback drain +
// ramp) on top of 516 MB mandatory traffic at ~8 TB/s marginal write rate.
// Structure-invariant across 5 structures + nt stores. Floor arithmetic:
// 320 (fill) + 63 (traffic) + ~90 (premium) = ~473 us = R1's 474.2.

constexpr int V = 256 * 256 * 48;   // 3,145,728 voxels per plane
constexpr int N_LABELS = 40;

__global__ __launch_bounds__(256)
void onehot_kernel(const float* __restrict__ mask, float* __restrict__ out) {
    const int i = (blockIdx.x * blockDim.x + threadIdx.x) * 4;  // voxel index
    const int n = blockIdx.y;                                   // label plane
    const float lab = (float)(n + 1);

    const float4 m = *reinterpret_cast<const float4*>(mask + i);

    float4 o;
    o.x = (m.x == lab) ? 1.0f : 0.0f;
    o.y = (m.y == lab) ? 1.0f : 0.0f;
    o.z = (m.z == lab) ? 1.0f : 0.0f;
    o.w = (m.w == lab) ? 1.0f : 0.0f;

    *reinterpret_cast<float4*>(out + (size_t)n * V + i) = o;
}

extern "C" void kernel_launch(void* const* d_in, const int* in_sizes, int n_in,
                              void* d_out, int out_size, void* d_ws, size_t ws_size,
                              hipStream_t stream) {
    const float* mask = (const float*)d_in[0];
    float* out = (float*)d_out;

    const int threads = 256;
    const int blocks_x = (V / 4) / threads;  // 3,072 chunks per plane
    dim3 grid(blocks_x, N_LABELS);           // 122,880 blocks total

    onehot_kernel<<<grid, threads, 0, stream>>>(mask, out);
}